// Round 5
// baseline (81.609 us; speedup 1.0000x reference)
//
#include <hip/hip_runtime.h>
#include <hip/hip_bf16.h>

// QueryGrouper: ball_query (first-K-in-index-order within radius) + grouping.
// B=4, N=8192, M=2048, C=128, K=32, radius=0.1, use_xyz from out_size.
//
// R5 (= R4 with compile fix): channel-staged gather, minimal staging
// amplification. Block = (channel-pair, batch, m-half), 1024 threads, 64KB LDS
// tile holding both channel rows interleaved. feat staged 2x total, idx
// int2-coalesced, stores packed 8B nontemporal (native clang vector type —
// __builtin_nontemporal_store rejects HIP_vector_type float2).

#define K_NEIGH 32
// f32(0.010000000000000002) — matches JAX weak-typed radius*radius bit-exactly.
#define R2_F32 0.009999999776482582f
#define CCH 128
#define NPTS 8192
#define MQ 2048

typedef float f32x2 __attribute__((ext_vector_type(2)));

__global__ __launch_bounds__(256) void ball_query_xyz_kernel(
    const float* __restrict__ xyz,      // (B,3,N)
    const float* __restrict__ new_xyz,  // (B,3,M)
    int* __restrict__ idxb,             // (B*M, K)
    float* __restrict__ out0,           // (B, CO, M, K)
    float* __restrict__ out1,           // (B, 3, M, K)
    int N, int M, int C, int use_xyz)
{
    __shared__ int lidx[4][K_NEIGH];
    const int wave = threadIdx.x >> 6;
    const int lane = threadIdx.x & 63;
    const int q = blockIdx.x * 4 + wave;           // query id in [0, B*M)
    const int b = q / M;
    const int m = q - b * M;

    const float* xb = xyz + (size_t)b * 3 * N;
    const float* nb = new_xyz + (size_t)b * 3 * M;
    const float qx = nb[m];
    const float qy = nb[M + m];
    const float qz = nb[2 * M + m];

    int cnt = 0;
    int first_found = 0;   // pad value: first in-ball index, or 0 if none

    for (int t0 = 0; t0 < N; t0 += 64) {
        const int i = t0 + lane;
        // match JAX: sub, square (no FMA), left-to-right sum, all f32 RN
        const float dx = xb[i]         - qx;
        const float dy = xb[N + i]     - qy;
        const float dz = xb[2 * N + i] - qz;
        const float d2 = __fadd_rn(__fadd_rn(__fmul_rn(dx, dx), __fmul_rn(dy, dy)),
                                   __fmul_rn(dz, dz));
        const bool in_ball = d2 < R2_F32;
        const unsigned long long mask = __ballot(in_ball);
        if (mask) {
            if (cnt == 0) {
                first_found = t0 + (__ffsll((unsigned long long)mask) - 1);
            }
            if (in_ball) {
                const int pos = cnt + __popcll(mask & ((1ull << lane) - 1ull));
                if (pos < K_NEIGH) lidx[wave][pos] = i;
            }
            cnt += __popcll(mask);
            if (cnt >= K_NEIGH) break;   // first K found (in index order)
        }
    }

    // make this wave's LDS writes visible to its own lanes
    asm volatile("s_waitcnt lgkmcnt(0)" ::: "memory");

    if (lane < K_NEIGH) {
        const int j = (lane < cnt) ? lidx[wave][lane] : first_found;
        idxb[(size_t)q * K_NEIGH + lane] = j;
        const float gx = xb[j]         - qx;
        const float gy = xb[N + j]     - qy;
        const float gz = xb[2 * N + j] - qz;
        const size_t MK = (size_t)M * K_NEIGH;
        const size_t o1 = (size_t)b * 3 * MK + (size_t)m * K_NEIGH + lane;
        out1[o1]          = gx;
        out1[o1 + MK]     = gy;
        out1[o1 + 2 * MK] = gz;
        if (use_xyz) {
            const size_t o0 = (size_t)b * (C + 3) * MK + (size_t)m * K_NEIGH + lane;
            out0[o0]          = gx;
            out0[o0 + MK]     = gy;
            out0[o0 + 2 * MK] = gz;
        }
    }
}

// Fixed geometry fast path: B=4, N=8192, M=2048, C=128.
// grid = 512: bid -> cg = bid>>3 (channel pair), b = (bid>>1)&3, mh = bid&1.
// Stage both channel rows interleaved (64KB), then 32768 items:
// thread t, pair-iter pi -> items {pi*2048 + 2t, +1}; int2 idx load,
// 2x ds_read_b64, 2x packed 8B nontemporal store (channels c0, c0+1).
__global__ __launch_bounds__(1024) void gather_chan2_kernel(
    const float* __restrict__ feat,  // (B,C,N)
    const int* __restrict__ idxb,    // (B*M,K)
    float* __restrict__ out0,        // (B,CO,M,K)
    int use_xyz)
{
    __shared__ f32x2 sf[NPTS];   // 64 KB, sf[j] = {feat[c0][j], feat[c0+1][j]}

    const int t   = threadIdx.x;
    const int bid = blockIdx.x;
    const int cg  = bid >> 3;          // 0..63
    const int b   = (bid >> 1) & 3;    // 0..3
    const int mh  = bid & 1;           // 0..1

    const int c0 = cg * 2;
    const float* f0 = feat + ((size_t)b * CCH + c0) * NPTS;
    const float* f1 = f0 + NPTS;

    #pragma unroll
    for (int it = 0; it < NPTS / 1024; ++it) {    // 8 iters
        const int i = t + it * 1024;
        f32x2 v; v.x = f0[i]; v.y = f1[i];
        sf[i] = v;
    }
    __syncthreads();

    const size_t MK = (size_t)MQ * K_NEIGH;
    const int CO   = use_xyz ? (CCH + 3) : CCH;
    const int coff = use_xyz ? 3 : 0;
    const int m0   = mh * (MQ / 2);

    const int2* ip2 = (const int2*)(idxb + ((size_t)b * MQ + m0) * K_NEIGH);
    float* o0 = out0 + ((size_t)b * CO + coff + c0) * MK + (size_t)m0 * K_NEIGH;
    float* o1 = o0 + MK;

    #pragma unroll 4
    for (int pi = 0; pi < 16; ++pi) {
        const int pt = pi * 1024 + t;
        const int2 jj = ip2[pt];
        const f32x2 va = sf[jj.x];
        const f32x2 vb = sf[jj.y];
        f32x2 s0; s0.x = va.x; s0.y = vb.x;
        f32x2 s1; s1.x = va.y; s1.y = vb.y;
        __builtin_nontemporal_store(s0, (f32x2*)(o0 + 2 * pt));
        __builtin_nontemporal_store(s1, (f32x2*)(o1 + 2 * pt));
    }
}

// Fallback gather (any shape): R1 structure.
__global__ __launch_bounds__(256) void gather_kernel(
    const float* __restrict__ xyz, const float* __restrict__ new_xyz,
    const float* __restrict__ feat, const int* __restrict__ idxb,
    float* __restrict__ out0, float* __restrict__ out1,
    int N, int M, int C, int use_xyz)
{
    const int tid = threadIdx.x;
    const int k = tid & 31;
    const int mloc = tid >> 5;
    const int mchunks = M >> 3;
    const int b = blockIdx.x / mchunks;
    const int m = (blockIdx.x - b * mchunks) * 8 + mloc;
    const int q = b * M + m;
    const int j = idxb[(size_t)q * K_NEIGH + k];
    const size_t xb = (size_t)b * 3 * N;
    const size_t nb = (size_t)b * 3 * M;
    const float gx = xyz[xb + j]         - new_xyz[nb + m];
    const float gy = xyz[xb + N + j]     - new_xyz[nb + M + m];
    const float gz = xyz[xb + 2 * N + j] - new_xyz[nb + 2 * M + m];
    const size_t MK = (size_t)M * K_NEIGH;
    const size_t o1 = (size_t)b * 3 * MK + (size_t)m * K_NEIGH + k;
    out1[o1] = gx; out1[o1 + MK] = gy; out1[o1 + 2 * MK] = gz;
    const int CO = use_xyz ? (C + 3) : C;
    size_t o0 = (size_t)b * CO * MK + (size_t)m * K_NEIGH + k;
    if (use_xyz) {
        out0[o0] = gx; out0[o0 + MK] = gy; out0[o0 + 2 * MK] = gz;
        o0 += 3 * MK;
    }
    const float* fb = feat + (size_t)b * C * N;
    #pragma unroll 4
    for (int c = 0; c < C; c += 4) {
        const float v0 = fb[(size_t)c * N + j];
        const float v1 = fb[(size_t)(c + 1) * N + j];
        const float v2 = fb[(size_t)(c + 2) * N + j];
        const float v3 = fb[(size_t)(c + 3) * N + j];
        out0[o0 + (size_t)c * MK]       = v0;
        out0[o0 + (size_t)(c + 1) * MK] = v1;
        out0[o0 + (size_t)(c + 2) * MK] = v2;
        out0[o0 + (size_t)(c + 3) * MK] = v3;
    }
}

extern "C" void kernel_launch(void* const* d_in, const int* in_sizes, int n_in,
                              void* d_out, int out_size, void* d_ws, size_t ws_size,
                              hipStream_t stream) {
    const float* new_xyz = (const float*)d_in[0];   // (B,3,M)
    const float* xyz     = (const float*)d_in[1];   // (B,3,N)
    const float* feat    = (const float*)d_in[2];   // (B,C,N)

    const int B = 4;                       // fixed by harness setup
    const int M = in_sizes[0] / (3 * B);   // 2048
    const int N = in_sizes[1] / (3 * B);   // 8192
    const int C = in_sizes[2] / (B * N);   // 128

    const long long sz_with = (long long)B * (C + 6) * M * K_NEIGH;
    const int use_xyz = (out_size == sz_with) ? 1 : 0;

    float* out0 = (float*)d_out;
    float* out1 = out0 + (size_t)B * (use_xyz ? (C + 3) : C) * M * K_NEIGH;

    int* idxb = (int*)d_ws;  // B*M*K ints = 1 MB
    const size_t idx_bytes = (size_t)B * M * K_NEIGH * sizeof(int);

    const bool fast = (B == 4) && (N == NPTS) && (M == MQ) && (C == CCH)
                      && (ws_size >= idx_bytes);

    ball_query_xyz_kernel<<<(B * M) / 4, 256, 0, stream>>>(
        xyz, new_xyz, idxb, out0, out1, N, M, C, use_xyz);

    if (fast) {
        gather_chan2_kernel<<<512, 1024, 0, stream>>>(feat, idxb, out0, use_xyz);
    } else {
        gather_kernel<<<B * (M / 8), 256, 0, stream>>>(xyz, new_xyz, feat, idxb,
                                                       out0, out1, N, M, C, use_xyz);
    }
}